// Round 4
// baseline (11.517 us; speedup 1.0000x reference)
//
#include <hip/hip_runtime.h>
#include <math.h>

// SimplePendulumSolver: theta'' = -g*sin(theta). Closed-form Jacobi-elliptic
// solution evaluated independently at every t_i (fully parallel), using the
// classical FOURIER SERIES of the pendulum instead of a backward-AGM am()
// recurrence -- the per-thread dependent chain drops ~4x.
//
//  E = v0^2/2 - g*cos(th0), W = sqrt(g)
//  Libration (E<g), k^2=(E+g)/(2g):
//     theta = 8 * sum_{n>=0} q^{n+1/2}/((2n+1)(1+q^{2n+1})) * sin((2n+1)*2pi*psi)
//     psi = (W t + u0)/(4K)      [one libration period == 4K in u]
//  Rotation (E>g), kr^2=2g/(E+g), Wr=sqrt((E+g)/2):
//     theta = 2*am(u) = 2pi*psi + sum_{n>=1} 4 q^n/(n(1+q^{2n})) sin(n*2pi*psi)
//     psi = (Wr t + u0)/(2K)
//  q (nome) via eps-series: eps=(1-sqrt(k'))/(2(1+sqrt(k'))), q=eps+2eps^5+15eps^9
//  K via AGM(1,k'); u0 = F(phi0,k) via one Carlson R_F.
//  Hardware v_sin_f32 takes REVOLUTIONS: sin(2pi*x) = v_sin(x); args kept <= ~11.
// Series sanity-checked: k=0.556 -> q=0.0231, theta_max = 1.188-0.0094+0.0001
//                        = 1.1794 == 2*asin(k). Harmonics decay by q^2 per term.

#define NSTEPS 65536
#define DT_SCALE 1e-3f
#define NH 6
#define PI_F 3.14159265358979323846f
#define TWO_PI_F 6.283185307179586f

__device__ __forceinline__ float vsin(float rev) {
    return __builtin_amdgcn_sinf(rev);  // sin(2*pi*rev)
}

// Carlson symmetric elliptic integral R_F(x,y,z), fixed-iteration f32.
__device__ __forceinline__ float carlson_rf(float x, float y, float z) {
#pragma unroll
    for (int it = 0; it < 7; ++it) {
        float sx = sqrtf(x), sy = sqrtf(y), sz = sqrtf(z);
        float lam = sx * (sy + sz) + sy * sz;
        x = 0.25f * (x + lam);
        y = 0.25f * (y + lam);
        z = 0.25f * (z + lam);
    }
    float ave = (x + y + z) * (1.0f / 3.0f);
    float dx = (ave - x) / ave, dy = (ave - y) / ave, dz = (ave - z) / ave;
    float e2 = dx * dy - dz * dz;
    float e3 = dx * dy * dz;
    return (1.0f + ((1.0f / 24.0f) * e2 - 0.1f - (3.0f / 44.0f) * e3) * e2 +
            (1.0f / 14.0f) * e3) / sqrtf(ave);
}

// K = pi/(2*AGM(1,kp)), 5 fixed iterations (quadratic convergence).
__device__ __forceinline__ float ellip_K(float kp) {
    float a = 1.0f, b = kp;
#pragma unroll
    for (int n = 0; n < 5; ++n) {
        float an = 0.5f * (a + b);
        float bn = sqrtf(a * b);
        a = an; b = bn;
    }
    return PI_F / (2.0f * a);
}

// nome q from k'^2 via eps-series (valid, fast-converging for k <= ~0.98)
__device__ __forceinline__ float nome_q(float kp) {
    float skp = sqrtf(kp);
    float eps = (1.0f - skp) / (2.0f * (1.0f + skp));
    float e2 = eps * eps;
    float e4 = e2 * e2;
    return eps * (1.0f + e4 * (2.0f + 15.0f * e4));  // eps + 2eps^5 + 15eps^9
}

// F(phi, k) for any phi, given K and mc=k'^2:  F(phi + n*pi) = F(phi) + 2nK.
__device__ __forceinline__ float ellip_F(float phi, float mc, float K) {
    float n0 = rintf(phi * (1.0f / PI_F));
    float pr = phi - n0 * PI_F;  // [-pi/2, pi/2]
    float s = sinf(pr), c = cosf(pr);
    float cc = c * c;
    return 2.0f * n0 * K + s * carlson_rf(cc, fmaf(mc * s, s, cc), 1.0f);
}

__global__ void pend_fourier(const float* __restrict__ y0,
                             const float* __restrict__ omega,
                             float* __restrict__ out) {
    int i = blockIdx.x * blockDim.x + threadIdx.x;
    if (i >= NSTEPS) return;

    float g   = omega[0];
    float th0 = y0[0];
    float v0  = y0[1];
    if (i == 0) { out[0] = th0; return; }

    float shift = TWO_PI_F * rintf(th0 * (1.0f / TWO_PI_F));
    float thc = th0 - shift;
    float E = fmaf(0.5f * v0, v0, -g * cosf(thc));
    float t = (float)i * DT_SCALE;

    if (E < g) {
        // ---- libration ----
        float mc = (g - E) / (2.0f * g);  // k'^2, cancellation-free
        float W  = sqrtf(g);
        float kp = sqrtf(mc);
        float K  = ellip_K(kp);
        float q  = nome_q(kp);

        // phi0 = atan2(sn0, cn0); scale-invariant form avoids dividing by k
        float phi0 = atan2f(sinf(0.5f * thc), v0 / (2.0f * W));
        float u0 = ellip_F(phi0, mc, K);

        float inv4K = 0.25f / K;
        float psi = fmaf(W * inv4K, t, u0 * inv4K);
        psi -= floorf(psi);  // [0,1) revolutions of the fundamental

        // theta - shift = sum c_n sin((2n+1)*2pi*psi)
        float p = sqrtf(q);   // q^{n+1/2}
        float d = q;          // q^{2n+1}
        float q2 = q * q;
        float acc = 0.0f;
#pragma unroll
        for (int n = 0; n < NH; ++n) {
            float cn = (8.0f / (float)(2 * n + 1)) * p / (1.0f + d);
            acc = fmaf(cn, vsin((float)(2 * n + 1) * psi), acc);
            p *= q;
            d *= q2;
        }
        out[i] = acc + shift;
    } else {
        // ---- rotation ----
        float sgn = (v0 >= 0.0f) ? 1.0f : -1.0f;
        float thr = sgn * thc;
        float mc = (E - g) / (E + g);  // kr'^2, cancellation-free
        float Wr = sqrtf(0.5f * (E + g));
        float kp = sqrtf(mc);
        float K  = ellip_K(kp);
        float q  = nome_q(kp);

        float u0 = ellip_F(0.5f * thr, mc, K);
        float inv2K = 0.5f / K;
        float psi = fmaf(Wr * inv2K, t, u0 * inv2K);
        float psir = psi - floorf(psi);

        // 2*am(u) = 2pi*psi + sum 4 q^n/(n(1+q^{2n})) sin(n*2pi*psi)
        float p = q;   // q^n
        float d = q * q;  // q^{2n}
        float q2 = q * q;
        float acc = TWO_PI_F * psi;
#pragma unroll
        for (int n = 1; n <= NH; ++n) {
            float cn = (4.0f / (float)n) * p / (1.0f + d);
            acc = fmaf(cn, vsin((float)n * psir), acc);
            p *= q;
            d *= q2;
        }
        out[i] = fmaf(sgn, acc, shift);
    }
}

extern "C" void kernel_launch(void* const* d_in, const int* in_sizes, int n_in,
                              void* d_out, int out_size, void* d_ws, size_t ws_size,
                              hipStream_t stream) {
    const float* y0    = (const float*)d_in[0];
    const float* omega = (const float*)d_in[2];
    float*       out   = (float*)d_out;

    hipLaunchKernelGGL(pend_fourier, dim3(NSTEPS / 256), dim3(256), 0, stream,
                       y0, omega, out);
}